// Round 7
// baseline (211.401 us; speedup 1.0000x reference)
//
#include <hip/hip_runtime.h>

#define DD 64
#define BW 256            // nodes per bucket (dst >> 8)
#define NBMAX 512         // supports n_nodes <= 131072
#define CAPB 4096         // fixed bucket capacity (mean 2560, +30 sigma)
#define CHUNK 4096        // edges per block in partition phase (~1 block/CU)
#define FILLPAD 16        // one fill counter per 64B line
#define SPAN_CAP 3072     // per-block csr LDS capacity (mean 640)

typedef unsigned short u16;
typedef unsigned char u8;
typedef u16 ushort8v __attribute__((ext_vector_type(8)));
typedef short s16x8 __attribute__((ext_vector_type(8)));
typedef float f32x4 __attribute__((ext_vector_type(4)));
typedef float f32x2 __attribute__((ext_vector_type(2)));

__device__ __forceinline__ float bf2f(u16 u) {
    union { unsigned u32; float f; } x; x.u32 = (unsigned)u << 16; return x.f;
}
__device__ __forceinline__ u16 f2bf(float f) {
    union { float f; unsigned u; } x; x.f = f;
    unsigned r = (x.u + 0x7fffu + ((x.u >> 16) & 1u)) >> 16;   // RTNE
    return (u16)r;
}

// pack 16 bf16 (two ushort8v) -> 16 fp8 bytes
__device__ __forceinline__ uint4 pack16_fp8(ushort8v s0, ushort8v s1) {
    uint4 pk;
    int w;
    w = __builtin_amdgcn_cvt_pk_fp8_f32(bf2f(s0[0]), bf2f(s0[1]), 0, false);
    w = __builtin_amdgcn_cvt_pk_fp8_f32(bf2f(s0[2]), bf2f(s0[3]), w, true);
    pk.x = (unsigned)w;
    w = __builtin_amdgcn_cvt_pk_fp8_f32(bf2f(s0[4]), bf2f(s0[5]), 0, false);
    w = __builtin_amdgcn_cvt_pk_fp8_f32(bf2f(s0[6]), bf2f(s0[7]), w, true);
    pk.y = (unsigned)w;
    w = __builtin_amdgcn_cvt_pk_fp8_f32(bf2f(s1[0]), bf2f(s1[1]), 0, false);
    w = __builtin_amdgcn_cvt_pk_fp8_f32(bf2f(s1[2]), bf2f(s1[3]), w, true);
    pk.z = (unsigned)w;
    w = __builtin_amdgcn_cvt_pk_fp8_f32(bf2f(s1[4]), bf2f(s1[5]), 0, false);
    w = __builtin_amdgcn_cvt_pk_fp8_f32(bf2f(s1[6]), bf2f(s1[7]), w, true);
    pk.w = (unsigned)w;
    return pk;
}

// decode 16 fp8 (uint4) and accumulate into a[0..15] — word-selects are literals
#define ACC16(u) do { \
    f32x2 _p; \
    _p = __builtin_amdgcn_cvt_pk_f32_fp8((int)(u).x, false); a[0]  += _p[0]; a[1]  += _p[1]; \
    _p = __builtin_amdgcn_cvt_pk_f32_fp8((int)(u).x, true);  a[2]  += _p[0]; a[3]  += _p[1]; \
    _p = __builtin_amdgcn_cvt_pk_f32_fp8((int)(u).y, false); a[4]  += _p[0]; a[5]  += _p[1]; \
    _p = __builtin_amdgcn_cvt_pk_f32_fp8((int)(u).y, true);  a[6]  += _p[0]; a[7]  += _p[1]; \
    _p = __builtin_amdgcn_cvt_pk_f32_fp8((int)(u).z, false); a[8]  += _p[0]; a[9]  += _p[1]; \
    _p = __builtin_amdgcn_cvt_pk_f32_fp8((int)(u).z, true);  a[10] += _p[0]; a[11] += _p[1]; \
    _p = __builtin_amdgcn_cvt_pk_f32_fp8((int)(u).w, false); a[12] += _p[0]; a[13] += _p[1]; \
    _p = __builtin_amdgcn_cvt_pk_f32_fp8((int)(u).w, true);  a[14] += _p[0]; a[15] += _p[1]; \
} while (0)

// ------- merged kernel: blocks [0, nb_chunk) = bucket partition (+ conv-weight cvt),
//         blocks [nb_chunk, nb_chunk+nb_gemm) = node linear (MFMA, f32 weights) -------
// part[b*CAPB + pos] = (src << 8) | (dst & 255)
__global__ __launch_bounds__(256) void k_partlin(
    const int* __restrict__ ei, int n_edges, int nb_chunk,
    int* __restrict__ fill, unsigned* __restrict__ part,
    const float* __restrict__ w1, const float* __restrict__ w2,
    const float* __restrict__ w3, const float* __restrict__ w4,
    u16* __restrict__ wb,
    const float* __restrict__ A, const float* __restrict__ W,
    const float* __restrict__ bias, u16* __restrict__ out, u8* __restrict__ out8,
    int n_nodes) {
    __shared__ int hist[NBMAX];
    __shared__ int curs[NBMAX];
    __shared__ u16 stage[64 * DD];   // 8 KB, lin-path epilogue transpose
    int t = threadIdx.x;
    if ((int)blockIdx.x < nb_chunk) {
        // ---- partition path ----
        {
            // convert the 4 conv weight matrices to bf16 (consumed only after k_build)
            int i = blockIdx.x * 256 + t;
            if (i < 4 * DD * DD) {
                int mat = i >> 12, off = i & 4095;
                const float* src = (mat == 0) ? w1 : (mat == 1) ? w2 : (mat == 2) ? w3 : w4;
                wb[DD * DD + i] = f2bf(src[off]);
            }
        }
        hist[t] = 0; hist[256 + t] = 0;
        __syncthreads();
        int c0 = blockIdx.x * CHUNK;
        int c1 = min(n_edges, c0 + CHUNK);
        int nloc = c1 - c0;
        int nvec = ((n_edges & 3) == 0) ? (nloc & ~3) : 0;   // int4 path needs 16B-aligned base
        // pass A: histogram (int4 dst loads, 4 edges/thread/iter)
        for (int e4 = t * 4; e4 < nvec; e4 += 1024) {
            int4 d4 = *(const int4*)(ei + n_edges + c0 + e4);
            atomicAdd(&hist[d4.x >> 8], 1);
            atomicAdd(&hist[d4.y >> 8], 1);
            atomicAdd(&hist[d4.z >> 8], 1);
            atomicAdd(&hist[d4.w >> 8], 1);
        }
        for (int e = nvec + t; e < nloc; e += 256)
            atomicAdd(&hist[ei[n_edges + c0 + e] >> 8], 1);
        __syncthreads();
        // prefix: reserve per-bucket ranges (padded counters, one per 64B line)
        #pragma unroll
        for (int k = 0; k < 2; ++k) {
            int idx = k * 256 + t;
            int h = hist[idx];
            int base = 0;
            if (h > 0) base = atomicAdd(&fill[idx * FILLPAD], h);
            curs[idx] = base;
        }
        __syncthreads();
        // pass B: scatter (int4 src+dst loads)
        for (int e4 = t * 4; e4 < nvec; e4 += 1024) {
            int4 d4 = *(const int4*)(ei + n_edges + c0 + e4);
            int4 s4 = *(const int4*)(ei + c0 + e4);
            {
                int b = d4.x >> 8; int pos = atomicAdd(&curs[b], 1);
                if (pos < CAPB) part[(size_t)b * CAPB + pos] = ((unsigned)s4.x << 8) | (unsigned)(d4.x & 255);
            }
            {
                int b = d4.y >> 8; int pos = atomicAdd(&curs[b], 1);
                if (pos < CAPB) part[(size_t)b * CAPB + pos] = ((unsigned)s4.y << 8) | (unsigned)(d4.y & 255);
            }
            {
                int b = d4.z >> 8; int pos = atomicAdd(&curs[b], 1);
                if (pos < CAPB) part[(size_t)b * CAPB + pos] = ((unsigned)s4.z << 8) | (unsigned)(d4.z & 255);
            }
            {
                int b = d4.w >> 8; int pos = atomicAdd(&curs[b], 1);
                if (pos < CAPB) part[(size_t)b * CAPB + pos] = ((unsigned)s4.w << 8) | (unsigned)(d4.w & 255);
            }
        }
        for (int e = nvec + t; e < nloc; e += 256) {
            int dst = ei[n_edges + c0 + e];
            int src = ei[c0 + e];
            int b = dst >> 8;
            int pos = atomicAdd(&curs[b], 1);
            if (pos < CAPB)
                part[(size_t)b * CAPB + pos] = ((unsigned)src << 8) | (unsigned)(dst & 255);
        }
    } else {
        // ---- node-linear path: fp32 x @ W^T + b -> bf16 h0 (+ fp8 shadow) ----
        int bid = (int)blockIdx.x - nb_chunk;
        int w = t >> 6;
        int lane = t & 63;
        int col = lane & 15;
        int quad = lane >> 4;
        int m0 = bid * 64 + w * 16;
        int arow = m0 + col;
        if (arow > n_nodes - 1) arow = n_nodes - 1;

        f32x4 acc[4];
        #pragma unroll
        for (int nt = 0; nt < 4; ++nt) {
            float bv = bias[nt * 16 + col];
            acc[nt] = (f32x4){bv, bv, bv, bv};
        }
        #pragma unroll
        for (int ks = 0; ks < 2; ++ks) {
            int k0 = ks * 32 + quad * 8;
            const float* p = A + (size_t)arow * DD + k0;
            float4 v0 = *(const float4*)p;
            float4 v1 = *(const float4*)(p + 4);
            s16x8 a;
            a[0] = (short)f2bf(v0.x); a[1] = (short)f2bf(v0.y);
            a[2] = (short)f2bf(v0.z); a[3] = (short)f2bf(v0.w);
            a[4] = (short)f2bf(v1.x); a[5] = (short)f2bf(v1.y);
            a[6] = (short)f2bf(v1.z); a[7] = (short)f2bf(v1.w);
            #pragma unroll
            for (int nt = 0; nt < 4; ++nt) {
                const float* wp = W + (size_t)(nt * 16 + col) * DD + k0;
                float4 b0 = *(const float4*)wp;
                float4 b1 = *(const float4*)(wp + 4);
                s16x8 bfr;
                bfr[0] = (short)f2bf(b0.x); bfr[1] = (short)f2bf(b0.y);
                bfr[2] = (short)f2bf(b0.z); bfr[3] = (short)f2bf(b0.w);
                bfr[4] = (short)f2bf(b1.x); bfr[5] = (short)f2bf(b1.y);
                bfr[6] = (short)f2bf(b1.z); bfr[7] = (short)f2bf(b1.w);
                acc[nt] = __builtin_amdgcn_mfma_f32_16x16x32_bf16(a, bfr, acc[nt], 0, 0, 0);
            }
        }
        // epilogue: stage C-tile in LDS (wave-private rows), coalesced 16B stores
        #pragma unroll
        for (int nt = 0; nt < 4; ++nt)
            #pragma unroll
            for (int i = 0; i < 4; ++i) {
                int rloc = w * 16 + quad * 4 + i;
                int dsw = (nt * 16 + col) ^ ((rloc & 3) << 4);   // seg-XOR bank swizzle
                stage[rloc * DD + dsw] = f2bf(acc[nt][i]);
            }
        __threadfence_block();   // same-wave LDS handoff
        {
            int rr = w * 16 + (lane >> 2);
            int sg = lane & 3;
            int m = bid * 64 + rr;
            if (m < n_nodes) {
                int se = (sg ^ (rr & 3)) * 16;
                ushort8v s0 = *(ushort8v*)(stage + rr * DD + se);
                ushort8v s1 = *(ushort8v*)(stage + rr * DD + se + 8);
                *(ushort8v*)(out + (size_t)m * DD + sg * 16) = s0;
                *(ushort8v*)(out + (size_t)m * DD + sg * 16 + 8) = s1;
                *(uint4*)(out8 + (size_t)m * DD + sg * 16) = pack16_fp8(s0, s1);
            }
        }
    }
}

// ------- per-bucket row_start/row_deg + csr build in LDS (256-node buckets) -------
__global__ __launch_bounds__(256) void k_build(const unsigned* __restrict__ part,
                        const int* __restrict__ fill,
                        int* __restrict__ row_start, int* __restrict__ row_deg,
                        int* __restrict__ csr, int n_nodes) {
    __shared__ int cnt_l[BW];
    __shared__ int sc[BW];
    __shared__ unsigned csr_l[CAPB];
    int t = threadIdx.x;
    int b = blockIdx.x;
    int beg = b * CAPB;
    int size = min(fill[b * FILLPAD], CAPB);

    cnt_l[t] = 0;
    __syncthreads();
    for (int j = t; j < size; j += 256)
        atomicAdd(&cnt_l[part[beg + j] & 255], 1);
    __syncthreads();
    int v0 = cnt_l[t];
    sc[t] = v0;
    cnt_l[t] = 0;
    __syncthreads();
    for (int off = 1; off < 256; off <<= 1) {
        int a = (t >= off) ? sc[t - off] : 0;
        __syncthreads();
        if (t >= off) sc[t] += a;
        __syncthreads();
    }
    {
        int n0 = b * BW + t;
        if (n0 < n_nodes) {
            row_start[n0] = beg + ((t == 0) ? 0 : sc[t - 1]);
            row_deg[n0] = v0;
        }
    }
    for (int j = t; j < size; j += 256) {
        unsigned p = part[beg + j];
        int dl = (int)(p & 255u);
        int pos = ((dl == 0) ? 0 : sc[dl - 1]) + atomicAdd(&cnt_l[dl], 1);
        csr_l[pos] = p >> 8;
    }
    __syncthreads();
    for (int i = t; i < size; i += 256) csr[beg + i] = (int)csr_l[i];
}

// ------- fused SAGE conv: LDS csr + fully-issued 12-slot predicated gather + bf16 MFMA -------
__global__ __launch_bounds__(256) void k_conv(
    const u16* __restrict__ h, const u8* __restrict__ h8,
    const int* __restrict__ row_start, const int* __restrict__ row_deg,
    const int* __restrict__ csr, const u8* __restrict__ zrow,
    const u16* __restrict__ Wl, const u16* __restrict__ Wr,
    const float* __restrict__ bias, u16* __restrict__ out, u8* __restrict__ out8,
    int n_nodes, int relu) {
    __shared__ u16 mean_l[64 * DD];        // 8 KB; reused as epilogue stage
    __shared__ int csr_s[SPAN_CAP + 12];   // block csr span (+pad for speculative reads)
    int t = threadIdx.x;
    int w = t >> 6, lane = t & 63;
    int m0 = blockIdx.x * 64;

    // stage this block's csr span (64 nodes = quarter-bucket => contiguous range)
    int nlast = min(m0 + 63, n_nodes - 1);
    int sbeg = row_start[m0];
    int span = row_start[nlast] + row_deg[nlast] - sbeg;
    bool lds_ok = (span <= SPAN_CAP);
    if (lds_ok) {
        for (int i = t; i < span; i += 256) csr_s[i] = csr[sbeg + i];
        if (t < 12) csr_s[span + t] = 0;   // pad for speculative slot reads
        __syncthreads();
    }

    {
        int nn = lane >> 2;   // node slot 0..15
        int r = lane & 3;     // dim quarter (16 fp8 = 16 B)
        int li = w * 16 + nn;                // local node index (this wave's slice)
        int n = m0 + li;
        int beg = 0, end = 0;
        if (n < n_nodes) { beg = row_start[n]; end = beg + row_deg[n]; }
        int deg = end - beg;
        float a[16];
        #pragma unroll
        for (int kk = 0; kk < 16; ++kk) a[kk] = 0.f;
        if (lds_ok) {
            int je = end - sbeg;
            size_t roff = (size_t)(r * 16);
            for (int jj = beg - sbeg; jj < je; jj += 12) {
                int cnt = je - jj;   // >=1
                // issue all 12 slot loads back-to-back; invalid slots read the zeros row
                #define GP(k) const u8* p##k = (k < cnt) ? (h8 + (size_t)csr_s[jj + k] * DD) : zrow;
                GP(0) GP(1) GP(2) GP(3) GP(4) GP(5) GP(6) GP(7) GP(8) GP(9) GP(10) GP(11)
                #undef GP
                uint4 u0  = *(const uint4*)(p0  + roff);
                uint4 u1  = *(const uint4*)(p1  + roff);
                uint4 u2  = *(const uint4*)(p2  + roff);
                uint4 u3  = *(const uint4*)(p3  + roff);
                uint4 u4  = *(const uint4*)(p4  + roff);
                uint4 u5  = *(const uint4*)(p5  + roff);
                uint4 u6  = *(const uint4*)(p6  + roff);
                uint4 u7  = *(const uint4*)(p7  + roff);
                uint4 u8_ = *(const uint4*)(p8  + roff);
                uint4 u9  = *(const uint4*)(p9  + roff);
                uint4 u10 = *(const uint4*)(p10 + roff);
                uint4 u11 = *(const uint4*)(p11 + roff);
                ACC16(u0);  ACC16(u1);  ACC16(u2);  ACC16(u3);
                ACC16(u4);  ACC16(u5);  ACC16(u6);  ACC16(u7);
                ACC16(u8_); ACC16(u9);  ACC16(u10); ACC16(u11);
            }
        } else {
            int j = beg;
            for (; j + 3 < end; j += 4) {
                int s0 = csr[j], s1 = csr[j + 1], s2 = csr[j + 2], s3 = csr[j + 3];
                uint4 u0 = *(const uint4*)(h8 + (size_t)s0 * DD + r * 16);
                uint4 u1 = *(const uint4*)(h8 + (size_t)s1 * DD + r * 16);
                uint4 u2 = *(const uint4*)(h8 + (size_t)s2 * DD + r * 16);
                uint4 u3 = *(const uint4*)(h8 + (size_t)s3 * DD + r * 16);
                ACC16(u0); ACC16(u1); ACC16(u2); ACC16(u3);
            }
            for (; j < end; ++j) {
                uint4 u0 = *(const uint4*)(h8 + (size_t)csr[j] * DD + r * 16);
                ACC16(u0);
            }
        }
        float inv = (deg > 0) ? 1.0f / (float)deg : 0.0f;
        ushort8v o0, o1;
        #pragma unroll
        for (int kk = 0; kk < 8; ++kk) { o0[kk] = f2bf(a[kk] * inv); o1[kk] = f2bf(a[8 + kk] * inv); }
        *(ushort8v*)(mean_l + li * DD + r * 16) = o0;      // OOB nodes write 0
        *(ushort8v*)(mean_l + li * DD + r * 16 + 8) = o1;
    }
    __threadfence_block();   // same-wave LDS handoff; no block barrier needed

    // phase 2: MFMA
    int col = lane & 15;
    int quad = lane >> 4;
    int arow = m0 + w * 16 + col;
    if (arow > n_nodes - 1) arow = n_nodes - 1;

    f32x4 acc[4];
    #pragma unroll
    for (int nt = 0; nt < 4; ++nt) {
        float bv = bias[nt * 16 + col];
        acc[nt] = (f32x4){bv, bv, bv, bv};
    }
    #pragma unroll
    for (int ks = 0; ks < 2; ++ks) {
        int k0 = ks * 32 + quad * 8;
        s16x8 am = *(const s16x8*)(mean_l + (w * 16 + col) * DD + k0);
        s16x8 ah = *(const s16x8*)(h + (size_t)arow * DD + k0);
        #pragma unroll
        for (int nt = 0; nt < 4; ++nt) {
            s16x8 bl = *(const s16x8*)(Wl + (nt * 16 + col) * DD + k0);
            acc[nt] = __builtin_amdgcn_mfma_f32_16x16x32_bf16(am, bl, acc[nt], 0, 0, 0);
            s16x8 br = *(const s16x8*)(Wr + (nt * 16 + col) * DD + k0);
            acc[nt] = __builtin_amdgcn_mfma_f32_16x16x32_bf16(ah, br, acc[nt], 0, 0, 0);
        }
    }
    // epilogue: stage C-tile in LDS (wave-private rows, mean_l fully consumed), coalesced stores
    #pragma unroll
    for (int nt = 0; nt < 4; ++nt)
        #pragma unroll
        for (int i = 0; i < 4; ++i) {
            float v = acc[nt][i];
            if (relu) v = fmaxf(v, 0.f);
            int rloc = w * 16 + quad * 4 + i;
            int dsw = (nt * 16 + col) ^ ((rloc & 3) << 4);   // seg-XOR bank swizzle
            mean_l[rloc * DD + dsw] = f2bf(v);
        }
    __threadfence_block();   // same-wave LDS handoff
    {
        int rr = w * 16 + (lane >> 2);
        int sg = lane & 3;
        int m = m0 + rr;
        if (m < n_nodes) {
            int se = (sg ^ (rr & 3)) * 16;
            ushort8v s0 = *(ushort8v*)(mean_l + rr * DD + se);
            ushort8v s1 = *(ushort8v*)(mean_l + rr * DD + se + 8);
            *(ushort8v*)(out + (size_t)m * DD + sg * 16) = s0;
            *(ushort8v*)(out + (size_t)m * DD + sg * 16 + 8) = s1;
            if (out8)
                *(uint4*)(out8 + (size_t)m * DD + sg * 16) = pack16_fp8(s0, s1);
        }
    }
}

// ---------------- preds: 64 edges per block (4 per wave x 4 iters), bf16 loads ----------------
__global__ void k_pred(const u16* __restrict__ h, const int* __restrict__ eli,
                       int n_label, float* __restrict__ out) {
    int t = threadIdx.x;
    int g = (t >> 3) & 1;
    int r = t & 7;
    #pragma unroll
    for (int it = 0; it < 4; ++it) {
        int e = blockIdx.x * 64 + it * 16 + (t >> 4);
        if (e < n_label) {
            int node = g ? eli[n_label + e] : eli[e];
            ushort8v v = *(const ushort8v*)(h + (size_t)node * DD + r * 8);
            float s = 0.f;
            #pragma unroll
            for (int kk = 0; kk < 8; ++kk) {
                float f = bf2f(v[kk]);
                s += f * __shfl_xor(f, 8, 64);   // pair with other endpoint, same octet
            }
            #pragma unroll
            for (int off = 1; off < 8; off <<= 1) s += __shfl_xor(s, off, 64);
            if ((t & 15) == 0) out[e] = s;
        }
    }
}

extern "C" void kernel_launch(void* const* d_in, const int* in_sizes, int n_in,
                              void* d_out, int out_size, void* d_ws, size_t ws_size,
                              hipStream_t stream) {
    const float* x     = (const float*)d_in[0];
    const int*   ei    = (const int*)d_in[1];
    const int*   eli   = (const int*)d_in[2];
    const float* W_lin = (const float*)d_in[3];
    const float* b_lin = (const float*)d_in[4];
    const float* Wl1   = (const float*)d_in[5];
    const float* bl1   = (const float*)d_in[6];
    const float* Wr1   = (const float*)d_in[7];
    const float* Wl2   = (const float*)d_in[8];
    const float* bl2   = (const float*)d_in[9];
    const float* Wr2   = (const float*)d_in[10];

    int n_nodes = in_sizes[0] / DD;
    int n_edges = in_sizes[1] / 2;
    int n_label = in_sizes[2] / 2;
    float* out = (float*)d_out;

    int nb = (n_nodes + BW - 1) / BW;     // buckets (391 for 100K)

    char* ws = (char*)d_ws;
    size_t hbytes = (size_t)n_nodes * DD * sizeof(u16);
    u16* hA   = (u16*)ws; ws += hbytes;
    u16* hB   = (u16*)ws; ws += hbytes;
    u8* h8A   = (u8*)ws;  ws += (size_t)n_nodes * DD;
    u8* h8B   = (u8*)ws;  ws += (size_t)n_nodes * DD;
    int* row_start = (int*)ws; ws += (size_t)((n_nodes + 3) & ~3) * sizeof(int);
    int* row_deg   = (int*)ws; ws += (size_t)((n_nodes + 3) & ~3) * sizeof(int);
    int* fill      = (int*)ws; ws += (size_t)NBMAX * FILLPAD * sizeof(int);
    u8* zrow       = (u8*)ws; ws += 64;            // 64B zeros row (gather padding target)
    u16* wb        = (u16*)ws; ws += 5 * DD * DD * sizeof(u16);
    unsigned* part = (unsigned*)ws; ws += (size_t)nb * CAPB * sizeof(unsigned);
    int* csr       = (int*)ws; ws += (size_t)nb * CAPB * sizeof(int);

    int nb_chunk = (n_edges + CHUNK - 1) / CHUNK;
    int nb_gemm = (n_nodes + 63) / 64;
    int nb_pred = (n_label + 63) / 64;

    // partition + node-linear fused (independent work, disjoint block ranges)
    // memset covers fill counters AND the zrow (contiguous)
    (void)hipMemsetAsync(fill, 0, (size_t)NBMAX * FILLPAD * sizeof(int) + 64, stream);
    k_partlin<<<nb_chunk + nb_gemm, 256, 0, stream>>>(
        ei, n_edges, nb_chunk, fill, part,
        Wl1, Wr1, Wl2, Wr2, wb,
        x, W_lin, b_lin, hA, h8A, n_nodes);

    k_build<<<nb, 256, 0, stream>>>(part, fill, row_start, row_deg, csr, n_nodes);

    // conv1 (12-slot predicated gather; writes bf16 + fp8 shadow)
    k_conv<<<nb_gemm, 256, 0, stream>>>(hA, h8A, row_start, row_deg, csr, zrow,
                                        wb + 4096, wb + 2 * 4096, bl1, hB, h8B, n_nodes, 1);

    // conv2 (bf16 out only)
    k_conv<<<nb_gemm, 256, 0, stream>>>(hB, h8B, row_start, row_deg, csr, zrow,
                                        wb + 3 * 4096, wb + 4 * 4096, bl2, hA, nullptr, n_nodes, 0);

    // edge classifier (bf16)
    k_pred<<<nb_pred, 256, 0, stream>>>(hA, eli, n_label, out);
}

// Round 8
// 193.705 us; speedup vs baseline: 1.0914x; 1.0914x over previous
//
#include <hip/hip_runtime.h>

#define DD 64
#define BW 256            // nodes per bucket (dst >> 8)
#define NBMAX 512         // supports n_nodes <= 131072
#define CAPB 4096         // fixed bucket capacity (mean 2560, +30 sigma)
#define CHUNK 8192        // edges per block in partition phase
#define FILLPAD 16        // one fill counter per 64B line
#define SPAN_CAP 3072     // per-block csr LDS capacity (mean 640)

typedef unsigned short u16;
typedef unsigned char u8;
typedef u16 ushort8v __attribute__((ext_vector_type(8)));
typedef short s16x8 __attribute__((ext_vector_type(8)));
typedef float f32x4 __attribute__((ext_vector_type(4)));
typedef float f32x2 __attribute__((ext_vector_type(2)));

__device__ __forceinline__ float bf2f(u16 u) {
    union { unsigned u32; float f; } x; x.u32 = (unsigned)u << 16; return x.f;
}
__device__ __forceinline__ u16 f2bf(float f) {
    union { float f; unsigned u; } x; x.f = f;
    unsigned r = (x.u + 0x7fffu + ((x.u >> 16) & 1u)) >> 16;   // RTNE
    return (u16)r;
}

// pack 16 bf16 (two ushort8v) -> 16 fp8 bytes
__device__ __forceinline__ uint4 pack16_fp8(ushort8v s0, ushort8v s1) {
    uint4 pk;
    int w;
    w = __builtin_amdgcn_cvt_pk_fp8_f32(bf2f(s0[0]), bf2f(s0[1]), 0, false);
    w = __builtin_amdgcn_cvt_pk_fp8_f32(bf2f(s0[2]), bf2f(s0[3]), w, true);
    pk.x = (unsigned)w;
    w = __builtin_amdgcn_cvt_pk_fp8_f32(bf2f(s0[4]), bf2f(s0[5]), 0, false);
    w = __builtin_amdgcn_cvt_pk_fp8_f32(bf2f(s0[6]), bf2f(s0[7]), w, true);
    pk.y = (unsigned)w;
    w = __builtin_amdgcn_cvt_pk_fp8_f32(bf2f(s1[0]), bf2f(s1[1]), 0, false);
    w = __builtin_amdgcn_cvt_pk_fp8_f32(bf2f(s1[2]), bf2f(s1[3]), w, true);
    pk.z = (unsigned)w;
    w = __builtin_amdgcn_cvt_pk_fp8_f32(bf2f(s1[4]), bf2f(s1[5]), 0, false);
    w = __builtin_amdgcn_cvt_pk_fp8_f32(bf2f(s1[6]), bf2f(s1[7]), w, true);
    pk.w = (unsigned)w;
    return pk;
}

// decode 16 fp8 (uint4) and accumulate into a[0..15] — word-selects are literals
#define ACC16(u) do { \
    f32x2 _p; \
    _p = __builtin_amdgcn_cvt_pk_f32_fp8((int)(u).x, false); a[0]  += _p[0]; a[1]  += _p[1]; \
    _p = __builtin_amdgcn_cvt_pk_f32_fp8((int)(u).x, true);  a[2]  += _p[0]; a[3]  += _p[1]; \
    _p = __builtin_amdgcn_cvt_pk_f32_fp8((int)(u).y, false); a[4]  += _p[0]; a[5]  += _p[1]; \
    _p = __builtin_amdgcn_cvt_pk_f32_fp8((int)(u).y, true);  a[6]  += _p[0]; a[7]  += _p[1]; \
    _p = __builtin_amdgcn_cvt_pk_f32_fp8((int)(u).z, false); a[8]  += _p[0]; a[9]  += _p[1]; \
    _p = __builtin_amdgcn_cvt_pk_f32_fp8((int)(u).z, true);  a[10] += _p[0]; a[11] += _p[1]; \
    _p = __builtin_amdgcn_cvt_pk_f32_fp8((int)(u).w, false); a[12] += _p[0]; a[13] += _p[1]; \
    _p = __builtin_amdgcn_cvt_pk_f32_fp8((int)(u).w, true);  a[14] += _p[0]; a[15] += _p[1]; \
} while (0)

// ------- merged kernel: blocks [0, nb_chunk) = bucket partition (+ conv-weight cvt),
//         blocks [nb_chunk, nb_chunk+nb_gemm) = node linear (MFMA, f32 weights) -------
// part[b*CAPB + pos] = (src << 8) | (dst & 255)
__global__ __launch_bounds__(256) void k_partlin(
    const int* __restrict__ ei, int n_edges, int nb_chunk,
    int* __restrict__ fill, unsigned* __restrict__ part,
    const float* __restrict__ w1, const float* __restrict__ w2,
    const float* __restrict__ w3, const float* __restrict__ w4,
    u16* __restrict__ wb,
    const float* __restrict__ A, const float* __restrict__ W,
    const float* __restrict__ bias, u16* __restrict__ out, u8* __restrict__ out8,
    int n_nodes) {
    __shared__ int hist[NBMAX];
    __shared__ int curs[NBMAX];
    __shared__ u16 stage[64 * DD];   // 8 KB, lin-path epilogue transpose
    int t = threadIdx.x;
    if ((int)blockIdx.x < nb_chunk) {
        // ---- partition path ----
        {
            // convert the 4 conv weight matrices to bf16 (consumed only after k_build)
            int i = blockIdx.x * 256 + t;
            if (i < 4 * DD * DD) {
                int mat = i >> 12, off = i & 4095;
                const float* src = (mat == 0) ? w1 : (mat == 1) ? w2 : (mat == 2) ? w3 : w4;
                wb[DD * DD + i] = f2bf(src[off]);
            }
        }
        hist[t] = 0; hist[256 + t] = 0;
        __syncthreads();
        int c0 = blockIdx.x * CHUNK;
        int c1 = min(n_edges, c0 + CHUNK);
        int nloc = c1 - c0;
        int nvec = ((n_edges & 3) == 0) ? (nloc & ~3) : 0;   // int4 path needs 16B-aligned base
        // pass A: histogram (int4 dst loads, 4 edges/thread/iter)
        for (int e4 = t * 4; e4 < nvec; e4 += 1024) {
            int4 d4 = *(const int4*)(ei + n_edges + c0 + e4);
            atomicAdd(&hist[d4.x >> 8], 1);
            atomicAdd(&hist[d4.y >> 8], 1);
            atomicAdd(&hist[d4.z >> 8], 1);
            atomicAdd(&hist[d4.w >> 8], 1);
        }
        for (int e = nvec + t; e < nloc; e += 256)
            atomicAdd(&hist[ei[n_edges + c0 + e] >> 8], 1);
        __syncthreads();
        // prefix: reserve per-bucket ranges (padded counters, one per 64B line)
        #pragma unroll
        for (int k = 0; k < 2; ++k) {
            int idx = k * 256 + t;
            int h = hist[idx];
            int base = 0;
            if (h > 0) base = atomicAdd(&fill[idx * FILLPAD], h);
            curs[idx] = base;
        }
        __syncthreads();
        // pass B: scatter (int4 src+dst loads)
        for (int e4 = t * 4; e4 < nvec; e4 += 1024) {
            int4 d4 = *(const int4*)(ei + n_edges + c0 + e4);
            int4 s4 = *(const int4*)(ei + c0 + e4);
            {
                int b = d4.x >> 8; int pos = atomicAdd(&curs[b], 1);
                if (pos < CAPB) part[(size_t)b * CAPB + pos] = ((unsigned)s4.x << 8) | (unsigned)(d4.x & 255);
            }
            {
                int b = d4.y >> 8; int pos = atomicAdd(&curs[b], 1);
                if (pos < CAPB) part[(size_t)b * CAPB + pos] = ((unsigned)s4.y << 8) | (unsigned)(d4.y & 255);
            }
            {
                int b = d4.z >> 8; int pos = atomicAdd(&curs[b], 1);
                if (pos < CAPB) part[(size_t)b * CAPB + pos] = ((unsigned)s4.z << 8) | (unsigned)(d4.z & 255);
            }
            {
                int b = d4.w >> 8; int pos = atomicAdd(&curs[b], 1);
                if (pos < CAPB) part[(size_t)b * CAPB + pos] = ((unsigned)s4.w << 8) | (unsigned)(d4.w & 255);
            }
        }
        for (int e = nvec + t; e < nloc; e += 256) {
            int dst = ei[n_edges + c0 + e];
            int src = ei[c0 + e];
            int b = dst >> 8;
            int pos = atomicAdd(&curs[b], 1);
            if (pos < CAPB)
                part[(size_t)b * CAPB + pos] = ((unsigned)src << 8) | (unsigned)(dst & 255);
        }
    } else {
        // ---- node-linear path: fp32 x @ W^T + b -> bf16 h0 (+ fp8 shadow) ----
        int bid = (int)blockIdx.x - nb_chunk;
        int w = t >> 6;
        int lane = t & 63;
        int col = lane & 15;
        int quad = lane >> 4;
        int m0 = bid * 64 + w * 16;
        int arow = m0 + col;
        if (arow > n_nodes - 1) arow = n_nodes - 1;

        f32x4 acc[4];
        #pragma unroll
        for (int nt = 0; nt < 4; ++nt) {
            float bv = bias[nt * 16 + col];
            acc[nt] = (f32x4){bv, bv, bv, bv};
        }
        #pragma unroll
        for (int ks = 0; ks < 2; ++ks) {
            int k0 = ks * 32 + quad * 8;
            const float* p = A + (size_t)arow * DD + k0;
            float4 v0 = *(const float4*)p;
            float4 v1 = *(const float4*)(p + 4);
            s16x8 a;
            a[0] = (short)f2bf(v0.x); a[1] = (short)f2bf(v0.y);
            a[2] = (short)f2bf(v0.z); a[3] = (short)f2bf(v0.w);
            a[4] = (short)f2bf(v1.x); a[5] = (short)f2bf(v1.y);
            a[6] = (short)f2bf(v1.z); a[7] = (short)f2bf(v1.w);
            #pragma unroll
            for (int nt = 0; nt < 4; ++nt) {
                const float* wp = W + (size_t)(nt * 16 + col) * DD + k0;
                float4 b0 = *(const float4*)wp;
                float4 b1 = *(const float4*)(wp + 4);
                s16x8 bfr;
                bfr[0] = (short)f2bf(b0.x); bfr[1] = (short)f2bf(b0.y);
                bfr[2] = (short)f2bf(b0.z); bfr[3] = (short)f2bf(b0.w);
                bfr[4] = (short)f2bf(b1.x); bfr[5] = (short)f2bf(b1.y);
                bfr[6] = (short)f2bf(b1.z); bfr[7] = (short)f2bf(b1.w);
                acc[nt] = __builtin_amdgcn_mfma_f32_16x16x32_bf16(a, bfr, acc[nt], 0, 0, 0);
            }
        }
        // epilogue: stage C-tile in LDS (wave-private rows), coalesced 16B stores
        #pragma unroll
        for (int nt = 0; nt < 4; ++nt)
            #pragma unroll
            for (int i = 0; i < 4; ++i) {
                int rloc = w * 16 + quad * 4 + i;
                int dsw = (nt * 16 + col) ^ ((rloc & 3) << 4);   // seg-XOR bank swizzle
                stage[rloc * DD + dsw] = f2bf(acc[nt][i]);
            }
        __threadfence_block();   // same-wave LDS handoff
        {
            int rr = w * 16 + (lane >> 2);
            int sg = lane & 3;
            int m = bid * 64 + rr;
            if (m < n_nodes) {
                int se = (sg ^ (rr & 3)) * 16;
                ushort8v s0 = *(ushort8v*)(stage + rr * DD + se);
                ushort8v s1 = *(ushort8v*)(stage + rr * DD + se + 8);
                *(ushort8v*)(out + (size_t)m * DD + sg * 16) = s0;
                *(ushort8v*)(out + (size_t)m * DD + sg * 16 + 8) = s1;
                *(uint4*)(out8 + (size_t)m * DD + sg * 16) = pack16_fp8(s0, s1);
            }
        }
    }
}

// ------- per-bucket row_start/row_deg + csr build in LDS (256-node buckets) -------
__global__ __launch_bounds__(256) void k_build(const unsigned* __restrict__ part,
                        const int* __restrict__ fill,
                        int* __restrict__ row_start, int* __restrict__ row_deg,
                        int* __restrict__ csr, int n_nodes) {
    __shared__ int cnt_l[BW];
    __shared__ int sc[BW];
    __shared__ unsigned csr_l[CAPB];
    int t = threadIdx.x;
    int b = blockIdx.x;
    int beg = b * CAPB;
    int size = min(fill[b * FILLPAD], CAPB);

    cnt_l[t] = 0;
    __syncthreads();
    for (int j = t; j < size; j += 256)
        atomicAdd(&cnt_l[part[beg + j] & 255], 1);
    __syncthreads();
    int v0 = cnt_l[t];
    sc[t] = v0;
    cnt_l[t] = 0;
    __syncthreads();
    for (int off = 1; off < 256; off <<= 1) {
        int a = (t >= off) ? sc[t - off] : 0;
        __syncthreads();
        if (t >= off) sc[t] += a;
        __syncthreads();
    }
    {
        int n0 = b * BW + t;
        if (n0 < n_nodes) {
            row_start[n0] = beg + ((t == 0) ? 0 : sc[t - 1]);
            row_deg[n0] = v0;
        }
    }
    for (int j = t; j < size; j += 256) {
        unsigned p = part[beg + j];
        int dl = (int)(p & 255u);
        int pos = ((dl == 0) ? 0 : sc[dl - 1]) + atomicAdd(&cnt_l[dl], 1);
        csr_l[pos] = p >> 8;
    }
    __syncthreads();
    for (int i = t; i < size; i += 256) csr[beg + i] = (int)csr_l[i];
}

// ------- fused SAGE conv: LDS-staged csr + 2-deep pipelined fp8 gather + bf16 MFMA -------
__global__ __launch_bounds__(256) void k_conv(
    const u16* __restrict__ h, const u8* __restrict__ h8,
    const int* __restrict__ row_start, const int* __restrict__ row_deg,
    const int* __restrict__ csr,
    const u16* __restrict__ Wl, const u16* __restrict__ Wr,
    const float* __restrict__ bias, u16* __restrict__ out, u8* __restrict__ out8,
    int n_nodes, int relu) {
    __shared__ u16 mean_l[64 * DD];   // 8 KB; reused as epilogue stage
    __shared__ int csr_s[SPAN_CAP];   // 12 KB, block csr span
    int t = threadIdx.x;
    int w = t >> 6, lane = t & 63;
    int m0 = blockIdx.x * 64;

    // stage this block's csr span (64 nodes = quarter-bucket => contiguous range)
    int nlast = min(m0 + 63, n_nodes - 1);
    int sbeg = row_start[m0];
    int span = row_start[nlast] + row_deg[nlast] - sbeg;
    bool lds_ok = (span <= SPAN_CAP);
    if (lds_ok) {
        for (int i = t; i < span; i += 256) csr_s[i] = csr[sbeg + i];
        __syncthreads();
    }

    {
        int nn = lane >> 2;   // node slot 0..15
        int r = lane & 3;     // dim quarter (16 fp8 = 16 B)
        int li = w * 16 + nn;                // local node index (this wave's slice)
        int n = m0 + li;
        int beg = 0, end = 0;
        if (n < n_nodes) { beg = row_start[n]; end = beg + row_deg[n]; }
        int deg = end - beg;
        float a[16];
        #pragma unroll
        for (int kk = 0; kk < 16; ++kk) a[kk] = 0.f;
        if (lds_ok) {
            int j = beg - sbeg, je = end - sbeg;
            if (j + 3 < je) {
                // prologue: issue batch 0
                int s0 = csr_s[j], s1 = csr_s[j + 1], s2 = csr_s[j + 2], s3 = csr_s[j + 3];
                uint4 u0 = *(const uint4*)(h8 + (size_t)s0 * DD + r * 16);
                uint4 u1 = *(const uint4*)(h8 + (size_t)s1 * DD + r * 16);
                uint4 u2 = *(const uint4*)(h8 + (size_t)s2 * DD + r * 16);
                uint4 u3 = *(const uint4*)(h8 + (size_t)s3 * DD + r * 16);
                j += 4;
                for (; j + 3 < je; j += 4) {
                    // issue batch i+1 before consuming batch i (8 lines in flight)
                    int t0 = csr_s[j], t1 = csr_s[j + 1], t2 = csr_s[j + 2], t3 = csr_s[j + 3];
                    uint4 v0 = *(const uint4*)(h8 + (size_t)t0 * DD + r * 16);
                    uint4 v1 = *(const uint4*)(h8 + (size_t)t1 * DD + r * 16);
                    uint4 v2 = *(const uint4*)(h8 + (size_t)t2 * DD + r * 16);
                    uint4 v3 = *(const uint4*)(h8 + (size_t)t3 * DD + r * 16);
                    ACC16(u0); ACC16(u1); ACC16(u2); ACC16(u3);
                    u0 = v0; u1 = v1; u2 = v2; u3 = v3;
                }
                ACC16(u0); ACC16(u1); ACC16(u2); ACC16(u3);
            }
            for (; j < je; ++j) {
                uint4 u0 = *(const uint4*)(h8 + (size_t)csr_s[j] * DD + r * 16);
                ACC16(u0);
            }
        } else {
            int j = beg;
            for (; j + 3 < end; j += 4) {
                int s0 = csr[j], s1 = csr[j + 1], s2 = csr[j + 2], s3 = csr[j + 3];
                uint4 u0 = *(const uint4*)(h8 + (size_t)s0 * DD + r * 16);
                uint4 u1 = *(const uint4*)(h8 + (size_t)s1 * DD + r * 16);
                uint4 u2 = *(const uint4*)(h8 + (size_t)s2 * DD + r * 16);
                uint4 u3 = *(const uint4*)(h8 + (size_t)s3 * DD + r * 16);
                ACC16(u0); ACC16(u1); ACC16(u2); ACC16(u3);
            }
            for (; j < end; ++j) {
                uint4 u0 = *(const uint4*)(h8 + (size_t)csr[j] * DD + r * 16);
                ACC16(u0);
            }
        }
        float inv = (deg > 0) ? 1.0f / (float)deg : 0.0f;
        ushort8v o0, o1;
        #pragma unroll
        for (int kk = 0; kk < 8; ++kk) { o0[kk] = f2bf(a[kk] * inv); o1[kk] = f2bf(a[8 + kk] * inv); }
        *(ushort8v*)(mean_l + li * DD + r * 16) = o0;      // OOB nodes write 0
        *(ushort8v*)(mean_l + li * DD + r * 16 + 8) = o1;
    }
    __threadfence_block();   // same-wave LDS handoff; no block barrier needed

    // phase 2: MFMA
    int col = lane & 15;
    int quad = lane >> 4;
    int arow = m0 + w * 16 + col;
    if (arow > n_nodes - 1) arow = n_nodes - 1;

    f32x4 acc[4];
    #pragma unroll
    for (int nt = 0; nt < 4; ++nt) {
        float bv = bias[nt * 16 + col];
        acc[nt] = (f32x4){bv, bv, bv, bv};
    }
    #pragma unroll
    for (int ks = 0; ks < 2; ++ks) {
        int k0 = ks * 32 + quad * 8;
        s16x8 am = *(const s16x8*)(mean_l + (w * 16 + col) * DD + k0);
        s16x8 ah = *(const s16x8*)(h + (size_t)arow * DD + k0);
        #pragma unroll
        for (int nt = 0; nt < 4; ++nt) {
            s16x8 bl = *(const s16x8*)(Wl + (nt * 16 + col) * DD + k0);
            acc[nt] = __builtin_amdgcn_mfma_f32_16x16x32_bf16(am, bl, acc[nt], 0, 0, 0);
            s16x8 br = *(const s16x8*)(Wr + (nt * 16 + col) * DD + k0);
            acc[nt] = __builtin_amdgcn_mfma_f32_16x16x32_bf16(ah, br, acc[nt], 0, 0, 0);
        }
    }
    // epilogue: stage C-tile in LDS (wave-private rows, mean_l fully consumed), coalesced stores
    #pragma unroll
    for (int nt = 0; nt < 4; ++nt)
        #pragma unroll
        for (int i = 0; i < 4; ++i) {
            float v = acc[nt][i];
            if (relu) v = fmaxf(v, 0.f);
            int rloc = w * 16 + quad * 4 + i;
            int dsw = (nt * 16 + col) ^ ((rloc & 3) << 4);   // seg-XOR bank swizzle
            mean_l[rloc * DD + dsw] = f2bf(v);
        }
    __threadfence_block();   // same-wave LDS handoff
    {
        int rr = w * 16 + (lane >> 2);
        int sg = lane & 3;
        int m = m0 + rr;
        if (m < n_nodes) {
            int se = (sg ^ (rr & 3)) * 16;
            ushort8v s0 = *(ushort8v*)(mean_l + rr * DD + se);
            ushort8v s1 = *(ushort8v*)(mean_l + rr * DD + se + 8);
            *(ushort8v*)(out + (size_t)m * DD + sg * 16) = s0;
            *(ushort8v*)(out + (size_t)m * DD + sg * 16 + 8) = s1;
            if (out8)
                *(uint4*)(out8 + (size_t)m * DD + sg * 16) = pack16_fp8(s0, s1);
        }
    }
}

// ---------------- preds: 64 edges per block (16 per wave-iter x 4), bf16 loads ----------------
__global__ void k_pred(const u16* __restrict__ h, const int* __restrict__ eli,
                       int n_label, float* __restrict__ out) {
    int t = threadIdx.x;
    int g = (t >> 3) & 1;
    int r = t & 7;
    #pragma unroll
    for (int it = 0; it < 4; ++it) {
        int e = blockIdx.x * 64 + it * 16 + (t >> 4);
        if (e < n_label) {
            int node = g ? eli[n_label + e] : eli[e];
            ushort8v v = *(const ushort8v*)(h + (size_t)node * DD + r * 8);
            float s = 0.f;
            #pragma unroll
            for (int kk = 0; kk < 8; ++kk) {
                float f = bf2f(v[kk]);
                s += f * __shfl_xor(f, 8, 64);   // pair with other endpoint, same octet
            }
            #pragma unroll
            for (int off = 1; off < 8; off <<= 1) s += __shfl_xor(s, off, 64);
            if ((t & 15) == 0) out[e] = s;
        }
    }
}

extern "C" void kernel_launch(void* const* d_in, const int* in_sizes, int n_in,
                              void* d_out, int out_size, void* d_ws, size_t ws_size,
                              hipStream_t stream) {
    const float* x     = (const float*)d_in[0];
    const int*   ei    = (const int*)d_in[1];
    const int*   eli   = (const int*)d_in[2];
    const float* W_lin = (const float*)d_in[3];
    const float* b_lin = (const float*)d_in[4];
    const float* Wl1   = (const float*)d_in[5];
    const float* bl1   = (const float*)d_in[6];
    const float* Wr1   = (const float*)d_in[7];
    const float* Wl2   = (const float*)d_in[8];
    const float* bl2   = (const float*)d_in[9];
    const float* Wr2   = (const float*)d_in[10];

    int n_nodes = in_sizes[0] / DD;
    int n_edges = in_sizes[1] / 2;
    int n_label = in_sizes[2] / 2;
    float* out = (float*)d_out;

    int nb = (n_nodes + BW - 1) / BW;     // buckets (391 for 100K)

    char* ws = (char*)d_ws;
    size_t hbytes = (size_t)n_nodes * DD * sizeof(u16);
    u16* hA   = (u16*)ws; ws += hbytes;
    u16* hB   = (u16*)ws; ws += hbytes;
    u8* h8A   = (u8*)ws;  ws += (size_t)n_nodes * DD;
    u8* h8B   = (u8*)ws;  ws += (size_t)n_nodes * DD;
    int* row_start = (int*)ws; ws += (size_t)((n_nodes + 3) & ~3) * sizeof(int);
    int* row_deg   = (int*)ws; ws += (size_t)((n_nodes + 3) & ~3) * sizeof(int);
    int* fill      = (int*)ws; ws += (size_t)NBMAX * FILLPAD * sizeof(int);
    u16* wb        = (u16*)ws; ws += 5 * DD * DD * sizeof(u16);
    unsigned* part = (unsigned*)ws; ws += (size_t)nb * CAPB * sizeof(unsigned);
    int* csr       = (int*)ws; ws += (size_t)nb * CAPB * sizeof(int);

    int nb_chunk = (n_edges + CHUNK - 1) / CHUNK;
    int nb_gemm = (n_nodes + 63) / 64;
    int nb_pred = (n_label + 63) / 64;

    // partition + node-linear fused (independent work, disjoint block ranges)
    (void)hipMemsetAsync(fill, 0, (size_t)NBMAX * FILLPAD * sizeof(int), stream);
    k_partlin<<<nb_chunk + nb_gemm, 256, 0, stream>>>(
        ei, n_edges, nb_chunk, fill, part,
        Wl1, Wr1, Wl2, Wr2, wb,
        x, W_lin, b_lin, hA, h8A, n_nodes);

    k_build<<<nb, 256, 0, stream>>>(part, fill, row_start, row_deg, csr, n_nodes);

    // conv1 (LDS csr + pipelined fp8 gather; writes bf16 + fp8 shadow)
    k_conv<<<nb_gemm, 256, 0, stream>>>(hA, h8A, row_start, row_deg, csr,
                                        wb + 4096, wb + 2 * 4096, bl1, hB, h8B, n_nodes, 1);

    // conv2 (bf16 out only)
    k_conv<<<nb_gemm, 256, 0, stream>>>(hB, h8B, row_start, row_deg, csr,
                                        wb + 3 * 4096, wb + 4 * 4096, bl2, hA, nullptr, n_nodes, 0);

    // edge classifier (bf16)
    k_pred<<<nb_pred, 256, 0, stream>>>(hA, eli, n_label, out);
}